// Round 1
// baseline (585.632 us; speedup 1.0000x reference)
//
#include <hip/hip_runtime.h>

#define B 64
#define T 512
#define E 512
#define H 64
#define NEG_INF (-1e30f)
#define QROWS 8
#define SCHUNK 128
#define KSTRIDE 66   // LDS row stride for k/v chunks: even (float2-aligned), worst 2-way bank alias (free)

// ---------------------------------------------------------------------------
// Kernel 1: fused q/k/v projections.  One block per (b,t) row.
// x row (512 f32) staged in LDS; threads 0..191 each compute one of the
// 3*64 projection outputs.  W reads are 256B-coalesced per 64-lane group and
// L2-resident (128 KB each).
// ---------------------------------------------------------------------------
__global__ __launch_bounds__(256) void proj_kernel(
    const float* __restrict__ x,
    const float* __restrict__ Wk,
    const float* __restrict__ Wq,
    const float* __restrict__ Wv,
    float* __restrict__ q, float* __restrict__ k, float* __restrict__ v)
{
    __shared__ float xs[E];
    const int row = blockIdx.x;            // 0 .. B*T-1
    const int tid = threadIdx.x;

    // stage x row: 256 threads x float2 = 512 floats
    {
        const float2* src = reinterpret_cast<const float2*>(x + (size_t)row * E);
        reinterpret_cast<float2*>(xs)[tid] = src[tid];
    }
    __syncthreads();

    if (tid < 192) {
        const int which = tid >> 6;        // 0:q 1:k 2:v
        const int h = tid & 63;
        const float* W = (which == 0) ? Wq : (which == 1) ? Wk : Wv;
        float* outp    = (which == 0) ? q  : (which == 1) ? k  : v;
        float acc = 0.f;
        #pragma unroll 8
        for (int e = 0; e < E; ++e)
            acc += xs[e] * W[e * H + h];   // xs broadcast; W coalesced per group
        outp[(size_t)row * H + h] = acc;
    }
}

// ---------------------------------------------------------------------------
// Kernel 2: flash-style causal attention.  One block = 8 query rows of one
// batch.  K/V chunks of 128 keys staged in LDS.  Thread layout: 8 groups of
// 32 lanes; group r owns query row t0+r.  Online softmax with the reference's
// finite -1e30 mask value (all-masked rows degrade to uniform, matching ref).
// ---------------------------------------------------------------------------
__global__ __launch_bounds__(256) void attn_kernel(
    const float* __restrict__ q, const float* __restrict__ k,
    const float* __restrict__ v, const int* __restrict__ attn_mask,
    float* __restrict__ out)
{
    __shared__ float qs[QROWS * H];              // 2 KB
    __shared__ float ks[SCHUNK * KSTRIDE];       // 33.8 KB
    __shared__ float vs[SCHUNK * KSTRIDE];       // 33.8 KB
    __shared__ float ps[QROWS * 132];            // 4.2 KB

    const int tid = threadIdx.x;
    const int b  = blockIdx.x >> 6;              // T/QROWS = 64 blocks per batch
    const int t0 = (blockIdx.x & 63) * QROWS;
    const int r  = tid >> 5;                     // query row within block [0,8)
    const int sl = tid & 31;                     // lane within row-group
    const int t  = t0 + r;                       // global query index

    // stage q rows: 256 threads x float2 = 512 floats
    {
        const float2* src = reinterpret_cast<const float2*>(q + ((size_t)b * T + t0) * H);
        reinterpret_cast<float2*>(qs)[tid] = src[tid];
    }

    float m = -INFINITY;
    float l = 0.f;
    float acc0 = 0.f, acc1 = 0.f;

    // causal: only chunks whose first key index <= t0+QROWS-1
    const int nchunk = (t0 + QROWS - 1) / SCHUNK + 1;

    for (int c = 0; c < nchunk; ++c) {
        __syncthreads();  // q ready (iter 0) / previous PV done reading vs,ps
        // cooperative K/V chunk load: 128x64 f32 each, float2-vectorized
        {
            const int s_base = c * SCHUNK;
            const float2* ksrc = reinterpret_cast<const float2*>(k + ((size_t)b * T + s_base) * H);
            const float2* vsrc = reinterpret_cast<const float2*>(v + ((size_t)b * T + s_base) * H);
            #pragma unroll
            for (int i = 0; i < 16; ++i) {
                int pidx = tid + i * 256;        // float2 index in [0,4096)
                int s  = pidx >> 5;              // 32 float2 per key row
                int hh = (pidx & 31) * 2;
                *reinterpret_cast<float2*>(&ks[s * KSTRIDE + hh]) = ksrc[pidx];
                *reinterpret_cast<float2*>(&vs[s * KSTRIDE + hh]) = vsrc[pidx];
            }
        }
        __syncthreads();

        // scores: each lane computes 4 keys (s = sl + 32j)
        float sc[4];
        #pragma unroll
        for (int j = 0; j < 4; ++j) {
            const int s = sl + 32 * j;
            float a = 0.f;
            #pragma unroll 8
            for (int h = 0; h < H; ++h)
                a += qs[r * H + h] * ks[s * KSTRIDE + h];
            a *= 0.125f;                          // H^-0.5
            const int sg = c * SCHUNK + s;
            if (sg > t || attn_mask[b * T + sg] == 0) a = NEG_INF;
            sc[j] = a;
        }

        // chunk max (width-32 shuffle reduce within row-group)
        float cmax = fmaxf(fmaxf(sc[0], sc[1]), fmaxf(sc[2], sc[3]));
        #pragma unroll
        for (int off = 16; off >= 1; off >>= 1)
            cmax = fmaxf(cmax, __shfl_xor(cmax, off, 32));

        const float m_new  = fmaxf(m, cmax);
        const float scalef = __expf(m - m_new);   // m=-inf on first chunk -> 0

        float csum = 0.f;
        #pragma unroll
        for (int j = 0; j < 4; ++j) {
            const int s = sl + 32 * j;
            const float p = __expf(sc[j] - m_new);
            ps[r * 132 + s] = p;                  // same-wave write/read: no barrier
            csum += p;
        }
        #pragma unroll
        for (int off = 16; off >= 1; off >>= 1)
            csum += __shfl_xor(csum, off, 32);

        l = l * scalef + csum;
        m = m_new;
        acc0 *= scalef; acc1 *= scalef;

        // PV: each lane owns h = sl and sl+32
        #pragma unroll 4
        for (int s = 0; s < SCHUNK; ++s) {
            const float w = ps[r * 132 + s];      // broadcast within group
            acc0 += w * vs[s * KSTRIDE + sl];
            acc1 += w * vs[s * KSTRIDE + sl + 32];
        }
    }

    const float invl = 1.f / l;
    float* op = out + ((size_t)b * T + t) * H;
    op[sl]      = acc0 * invl;
    op[sl + 32] = acc1 * invl;
}

// ---------------------------------------------------------------------------
extern "C" void kernel_launch(void* const* d_in, const int* in_sizes, int n_in,
                              void* d_out, int out_size, void* d_ws, size_t ws_size,
                              hipStream_t stream) {
    const float* x         = (const float*)d_in[0];
    const int*   attn_mask = (const int*)d_in[1];
    const float* Wk        = (const float*)d_in[2];
    const float* Wq        = (const float*)d_in[3];
    const float* Wv        = (const float*)d_in[4];
    float* out = (float*)d_out;

    // workspace: q,k,v fp32, 8.4 MB each (25.2 MB total)
    float* q = (float*)d_ws;
    float* k = q + (size_t)B * T * H;
    float* v = k + (size_t)B * T * H;

    proj_kernel<<<B * T, 256, 0, stream>>>(x, Wk, Wq, Wv, q, k, v);
    attn_kernel<<<B * (T / QROWS), 256, 0, stream>>>(q, k, v, attn_mask, out);
}

// Round 2
// 266.291 us; speedup vs baseline: 2.1992x; 2.1992x over previous
//
#include <hip/hip_runtime.h>

#define B 64
#define T 512
#define E 512
#define H 64
#define NEG_INF (-1e30f)

// ---------------- attention params (unchanged from round 1) ----------------
#define QROWS 8
#define SCHUNK 128
#define KSTRIDE 66

// ---------------- projection GEMM params ----------------
#define PBM 64     // block M tile
#define PBK 64     // K chunk
#define PN 192     // total output cols (q|k|v)
#define PSTR 72    // LDS row stride in bf16 elems (144B: 16B-aligned, ~4-way max)

using short8 = __attribute__((ext_vector_type(8))) short;
using f32x16 = __attribute__((ext_vector_type(16))) float;

// float -> bf16 bits, round-to-nearest-even
__device__ __forceinline__ unsigned short f2bf(float f) {
    unsigned int u = __float_as_uint(f);
    u += 0x7fffu + ((u >> 16) & 1u);
    return (unsigned short)(u >> 16);
}

// ---------------------------------------------------------------------------
// Kernel 1: fused q/k/v projection as one MFMA bf16 GEMM.
//   A = x (32768 x 512), B = [Wq|Wk|Wv] (512 x 192), C -> q,k,v (32768 x 64 each)
// Block: 64x192 tile, 4 waves, wave tile 32x96 via mfma_f32_32x32x16_bf16.
// Grid 512 -> 2 blocks/CU.  LDS: Xs 9.2KB + Ws(transposed) 27.6KB.
// ---------------------------------------------------------------------------
__global__ __launch_bounds__(256) void proj_gemm(
    const float* __restrict__ x,
    const float* __restrict__ Wq, const float* __restrict__ Wk,
    const float* __restrict__ Wv,
    float* __restrict__ q, float* __restrict__ k, float* __restrict__ v)
{
    __shared__ unsigned short Xs[PBM * PSTR];   // [row][k]  9216 B
    __shared__ unsigned short Ws[PN * PSTR];    // [col][k] (W transposed) 27648 B

    const int tid  = threadIdx.x;
    const int wid  = tid >> 6;
    const int lane = tid & 63;
    const int row0 = blockIdx.x * PBM;

    const int r  = lane & 31;          // A-row / B-col within 32x32 tile
    const int ko = (lane >> 5) * 8;    // k sub-offset (0 or 8) within K=16 step

    const int mrow  = (wid >> 1) * 32 + r;   // Xs row this lane reads
    const int cbase = (wid & 1) * 96;        // wave col base

    f32x16 acc[3] = {};                 // 3 tiles of 32 cols, zero-init

    for (int kc = 0; kc < E; kc += PBK) {
        __syncthreads();   // previous compute done reading LDS

        // ---- stage Xs: 64 rows x 64 k, f32 -> bf16, float4 reads ----
        #pragma unroll
        for (int p = 0; p < 4; ++p) {
            int f  = p * 256 + tid;        // float4 index, 16 per row
            int rr = f >> 4;
            int cc = (f & 15) * 4;
            float4 xv = *reinterpret_cast<const float4*>(
                &x[(size_t)(row0 + rr) * E + kc + cc]);
            ushort4 bv;
            bv.x = f2bf(xv.x); bv.y = f2bf(xv.y);
            bv.z = f2bf(xv.z); bv.w = f2bf(xv.w);
            *reinterpret_cast<ushort4*>(&Xs[rr * PSTR + cc]) = bv;
        }

        // ---- stage Ws transposed: Ws[col][kk] = W[kc+kk][col], float4 reads ----
        #pragma unroll
        for (int p = 0; p < 12; ++p) {
            int e  = p * 256 + tid;        // float4 index over 192x64/4 = 3072
            int kk = e / 48;               // 48 float4 per k-row (192 cols)
            int h  = (e % 48) * 4;         // col 0..188, groups never cross seg
            int seg = h >> 6;
            int hh  = h & 63;
            const float* W = (seg == 0) ? Wq : (seg == 1) ? Wk : Wv;
            float4 wv = *reinterpret_cast<const float4*>(
                &W[(size_t)(kc + kk) * H + hh]);
            Ws[(h + 0) * PSTR + kk] = f2bf(wv.x);
            Ws[(h + 1) * PSTR + kk] = f2bf(wv.y);
            Ws[(h + 2) * PSTR + kk] = f2bf(wv.z);
            Ws[(h + 3) * PSTR + kk] = f2bf(wv.w);
        }
        __syncthreads();

        // ---- MFMA: 4 K-steps of 16, 3 col-tiles per wave ----
        #pragma unroll
        for (int ks = 0; ks < PBK; ks += 16) {
            short8 a = *reinterpret_cast<const short8*>(&Xs[mrow * PSTR + ks + ko]);
            #pragma unroll
            for (int nt = 0; nt < 3; ++nt) {
                int col = cbase + nt * 32 + r;
                short8 b = *reinterpret_cast<const short8*>(&Ws[col * PSTR + ks + ko]);
                acc[nt] = __builtin_amdgcn_mfma_f32_32x32x16_bf16(a, b, acc[nt], 0, 0, 0);
            }
        }
    }

    // ---- epilogue: C/D layout col=lane&31, row=(reg&3)+8*(reg>>2)+4*(lane>>5) ----
    #pragma unroll
    for (int nt = 0; nt < 3; ++nt) {
        const int gc  = cbase + nt * 32 + r;   // global col 0..191
        const int seg = gc >> 6;
        const int hh  = gc & 63;
        float* outp = (seg == 0) ? q : (seg == 1) ? k : v;
        #pragma unroll
        for (int reg = 0; reg < 16; ++reg) {
            int drow = (reg & 3) + 8 * (reg >> 2) + 4 * (lane >> 5);
            outp[(size_t)(row0 + (wid >> 1) * 32 + drow) * H + hh] = acc[nt][reg];
        }
    }
}

// ---------------------------------------------------------------------------
// Kernel 2: flash-style causal attention (unchanged from round 1).
// ---------------------------------------------------------------------------
__global__ __launch_bounds__(256) void attn_kernel(
    const float* __restrict__ q, const float* __restrict__ k,
    const float* __restrict__ v, const int* __restrict__ attn_mask,
    float* __restrict__ out)
{
    __shared__ float qs[QROWS * H];
    __shared__ float ks[SCHUNK * KSTRIDE];
    __shared__ float vs[SCHUNK * KSTRIDE];
    __shared__ float ps[QROWS * 132];

    const int tid = threadIdx.x;
    const int b  = blockIdx.x >> 6;
    const int t0 = (blockIdx.x & 63) * QROWS;
    const int r  = tid >> 5;
    const int sl = tid & 31;
    const int t  = t0 + r;

    {
        const float2* src = reinterpret_cast<const float2*>(q + ((size_t)b * T + t0) * H);
        reinterpret_cast<float2*>(qs)[tid] = src[tid];
    }

    float m = -INFINITY;
    float l = 0.f;
    float acc0 = 0.f, acc1 = 0.f;

    const int nchunk = (t0 + QROWS - 1) / SCHUNK + 1;

    for (int c = 0; c < nchunk; ++c) {
        __syncthreads();
        {
            const int s_base = c * SCHUNK;
            const float2* ksrc = reinterpret_cast<const float2*>(k + ((size_t)b * T + s_base) * H);
            const float2* vsrc = reinterpret_cast<const float2*>(v + ((size_t)b * T + s_base) * H);
            #pragma unroll
            for (int i = 0; i < 16; ++i) {
                int pidx = tid + i * 256;
                int s  = pidx >> 5;
                int hh = (pidx & 31) * 2;
                *reinterpret_cast<float2*>(&ks[s * KSTRIDE + hh]) = ksrc[pidx];
                *reinterpret_cast<float2*>(&vs[s * KSTRIDE + hh]) = vsrc[pidx];
            }
        }
        __syncthreads();

        float sc[4];
        #pragma unroll
        for (int j = 0; j < 4; ++j) {
            const int s = sl + 32 * j;
            float a = 0.f;
            #pragma unroll 8
            for (int h = 0; h < H; ++h)
                a += qs[r * H + h] * ks[s * KSTRIDE + h];
            a *= 0.125f;
            const int sg = c * SCHUNK + s;
            if (sg > t || attn_mask[b * T + sg] == 0) a = NEG_INF;
            sc[j] = a;
        }

        float cmax = fmaxf(fmaxf(sc[0], sc[1]), fmaxf(sc[2], sc[3]));
        #pragma unroll
        for (int off = 16; off >= 1; off >>= 1)
            cmax = fmaxf(cmax, __shfl_xor(cmax, off, 32));

        const float m_new  = fmaxf(m, cmax);
        const float scalef = __expf(m - m_new);

        float csum = 0.f;
        #pragma unroll
        for (int j = 0; j < 4; ++j) {
            const int s = sl + 32 * j;
            const float p = __expf(sc[j] - m_new);
            ps[r * 132 + s] = p;
            csum += p;
        }
        #pragma unroll
        for (int off = 16; off >= 1; off >>= 1)
            csum += __shfl_xor(csum, off, 32);

        l = l * scalef + csum;
        m = m_new;
        acc0 *= scalef; acc1 *= scalef;

        #pragma unroll 4
        for (int s = 0; s < SCHUNK; ++s) {
            const float w = ps[r * 132 + s];
            acc0 += w * vs[s * KSTRIDE + sl];
            acc1 += w * vs[s * KSTRIDE + sl + 32];
        }
    }

    const float invl = 1.f / l;
    float* op = out + ((size_t)b * T + t) * H;
    op[sl]      = acc0 * invl;
    op[sl + 32] = acc1 * invl;
}

// ---------------------------------------------------------------------------
extern "C" void kernel_launch(void* const* d_in, const int* in_sizes, int n_in,
                              void* d_out, int out_size, void* d_ws, size_t ws_size,
                              hipStream_t stream) {
    const float* x         = (const float*)d_in[0];
    const int*   attn_mask = (const int*)d_in[1];
    const float* Wk        = (const float*)d_in[2];
    const float* Wq        = (const float*)d_in[3];
    const float* Wv        = (const float*)d_in[4];
    float* out = (float*)d_out;

    float* q = (float*)d_ws;
    float* k = q + (size_t)B * T * H;
    float* v = k + (size_t)B * T * H;

    proj_gemm<<<(B * T) / PBM, 256, 0, stream>>>(x, Wq, Wk, Wv, q, k, v);
    attn_kernel<<<B * (T / QROWS), 256, 0, stream>>>(q, k, v, attn_mask, out);
}

// Round 3
// 102.381 us; speedup vs baseline: 5.7202x; 2.6010x over previous
//
#include <hip/hip_runtime.h>

#define B 64
#define T 512
#define E 512
#define H 64
#define NEG_INF (-1e30f)

// ---------------- projection GEMM params ----------------
#define PBM 64
#define PBK 64
#define PN 192
#define PSTR 72

// ---------------- attention params ----------------
#define QB 128        // q rows per block (4 waves x 32)
#define CH 128        // keys per chunk
#define KSTR 72       // Ks LDS row stride (bf16 elems), 144B: 16B-aligned
#define VSTR 136      // Vt LDS row stride (bf16 elems), 272B: 16B-aligned

using short8 = __attribute__((ext_vector_type(8))) short;
using f32x16 = __attribute__((ext_vector_type(16))) float;

// float -> bf16 bits, round-to-nearest-even
__device__ __forceinline__ unsigned short f2bf(float f) {
    unsigned int u = __float_as_uint(f);
    u += 0x7fffu + ((u >> 16) & 1u);
    return (unsigned short)(u >> 16);
}
__device__ __forceinline__ unsigned int bfpack(float lo, float hi) {
    return ((unsigned int)f2bf(hi) << 16) | (unsigned int)f2bf(lo);
}

// ---------------------------------------------------------------------------
// Kernel 1: fused q/k/v projection GEMM (structure unchanged from round 2).
// New epilogue: q -> bf16 pre-scaled by 1/8, k -> bf16 row-major,
// v -> bf16 TRANSPOSED per batch: vT[b][h][t]  (stores were scalar anyway).
// ---------------------------------------------------------------------------
__global__ __launch_bounds__(256) void proj_gemm(
    const float* __restrict__ x,
    const float* __restrict__ Wq, const float* __restrict__ Wk,
    const float* __restrict__ Wv,
    unsigned short* __restrict__ qbf, unsigned short* __restrict__ kbf,
    unsigned short* __restrict__ vT)
{
    __shared__ unsigned short Xs[PBM * PSTR];
    __shared__ unsigned short Ws[PN * PSTR];

    const int tid  = threadIdx.x;
    const int wid  = tid >> 6;
    const int lane = tid & 63;
    const int row0 = blockIdx.x * PBM;

    const int r  = lane & 31;
    const int ko = (lane >> 5) * 8;

    const int mrow  = (wid >> 1) * 32 + r;
    const int cbase = (wid & 1) * 96;

    f32x16 acc[3] = {};

    for (int kc = 0; kc < E; kc += PBK) {
        __syncthreads();

        #pragma unroll
        for (int p = 0; p < 4; ++p) {
            int f  = p * 256 + tid;
            int rr = f >> 4;
            int cc = (f & 15) * 4;
            float4 xv = *reinterpret_cast<const float4*>(
                &x[(size_t)(row0 + rr) * E + kc + cc]);
            ushort4 bv;
            bv.x = f2bf(xv.x); bv.y = f2bf(xv.y);
            bv.z = f2bf(xv.z); bv.w = f2bf(xv.w);
            *reinterpret_cast<ushort4*>(&Xs[rr * PSTR + cc]) = bv;
        }

        #pragma unroll
        for (int p = 0; p < 12; ++p) {
            int e  = p * 256 + tid;
            int kk = e / 48;
            int h  = (e % 48) * 4;
            int seg = h >> 6;
            int hh  = h & 63;
            const float* W = (seg == 0) ? Wq : (seg == 1) ? Wk : Wv;
            float4 wv = *reinterpret_cast<const float4*>(
                &W[(size_t)(kc + kk) * H + hh]);
            Ws[(h + 0) * PSTR + kk] = f2bf(wv.x);
            Ws[(h + 1) * PSTR + kk] = f2bf(wv.y);
            Ws[(h + 2) * PSTR + kk] = f2bf(wv.z);
            Ws[(h + 3) * PSTR + kk] = f2bf(wv.w);
        }
        __syncthreads();

        #pragma unroll
        for (int ks = 0; ks < PBK; ks += 16) {
            short8 a = *reinterpret_cast<const short8*>(&Xs[mrow * PSTR + ks + ko]);
            #pragma unroll
            for (int nt = 0; nt < 3; ++nt) {
                int col = cbase + nt * 32 + r;
                short8 b = *reinterpret_cast<const short8*>(&Ws[col * PSTR + ks + ko]);
                acc[nt] = __builtin_amdgcn_mfma_f32_32x32x16_bf16(a, b, acc[nt], 0, 0, 0);
            }
        }
    }

    #pragma unroll
    for (int nt = 0; nt < 3; ++nt) {
        const int gc  = cbase + nt * 32 + r;
        const int seg = gc >> 6;
        const int hh  = gc & 63;
        #pragma unroll
        for (int reg = 0; reg < 16; ++reg) {
            int drow = (reg & 3) + 8 * (reg >> 2) + 4 * (lane >> 5);
            int grow = row0 + (wid >> 1) * 32 + drow;
            float val = acc[nt][reg];
            if (seg == 0) {
                qbf[(size_t)grow * H + hh] = f2bf(val * 0.125f);   // fold H^-0.5
            } else if (seg == 1) {
                kbf[(size_t)grow * H + hh] = f2bf(val);
            } else {
                int bb = grow >> 9, tt = grow & 511;
                vT[((size_t)bb * H + hh) * T + tt] = f2bf(val);
            }
        }
    }
}

// ---------------------------------------------------------------------------
// Kernel 2: MFMA flash attention.  Block = 128 q rows of one batch, 4 waves
// (wave w owns q rows t0+32w..+31).  Chunks of 128 keys staged in LDS.
// Swapped QK^T (mfma(K,Q)): lane owns q = t0w + (lane&31); scores lane-local.
// P converted to bf16 A-fragments in-register (packs + shfl_xor(32)).
// V consumed from the transposed vT layout -> all LDS reads are b128.
// ---------------------------------------------------------------------------
__global__ __launch_bounds__(256) void attn_mfma(
    const unsigned short* __restrict__ qbf,
    const unsigned short* __restrict__ kbf,
    const unsigned short* __restrict__ vT,
    const int* __restrict__ attn_mask,
    float* __restrict__ out)
{
    __shared__ unsigned short Ks[CH * KSTR];   // 18432 B
    __shared__ unsigned short Vt[H * VSTR];    // 17408 B
    __shared__ int msk[CH];

    const int tid  = threadIdx.x;
    const int wid  = tid >> 6;
    const int lane = tid & 63;
    const int hi   = lane >> 5;
    const int r    = lane & 31;

    const int b     = blockIdx.x >> 2;
    const int strip = blockIdx.x & 3;
    const int t0w   = strip * QB + wid * 32;    // wave's first q row
    const int tq    = t0w + r;                  // this lane's q row

    // hoisted Q fragments (already scaled by 1/8)
    short8 qf[4];
    #pragma unroll
    for (int ks = 0; ks < 4; ++ks)
        qf[ks] = *reinterpret_cast<const short8*>(
            &qbf[((size_t)b * T + t0w + r) * H + ks * 16 + hi * 8]);

    f32x16 accO[2] = {};
    float m = -INFINITY, lsum = 0.f;

    const int nchunk = strip + 1;
    for (int c = 0; c < nchunk; ++c) {
        const int kbase = c * CH;
        __syncthreads();                        // prev compute done with LDS
        #pragma unroll
        for (int p = 0; p < 4; ++p) {           // stage K: 128 x 64 bf16
            int u = tid + p * 256;
            int row = u >> 3, o8 = (u & 7) * 8;
            *reinterpret_cast<short8*>(&Ks[row * KSTR + o8]) =
                *reinterpret_cast<const short8*>(
                    &kbf[((size_t)b * T + kbase + row) * H + o8]);
        }
        #pragma unroll
        for (int p = 0; p < 4; ++p) {           // stage V^T: 64 x 128 bf16
            int u = tid + p * 256;
            int h = u >> 4, j8 = (u & 15) * 8;
            *reinterpret_cast<short8*>(&Vt[h * VSTR + j8]) =
                *reinterpret_cast<const short8*>(
                    &vT[((size_t)b * H + h) * T + kbase + j8]);
        }
        if (tid < CH) msk[tid] = attn_mask[b * T + kbase + tid];
        __syncthreads();

        // wave-uniform count of 32-key blocks this wave needs (>=1 always)
        const int nkb = min(4, ((t0w + 31 - kbase) >> 5) + 1);

        // ---- QK^T swapped: sc[kb] col=q(lane&31), row=key-in-block ----
        f32x16 sc[4];
        #pragma unroll
        for (int kb = 0; kb < 4; ++kb) {
            if (kb < nkb) {
                f32x16 a = {};
                #pragma unroll
                for (int ks = 0; ks < 4; ++ks) {
                    short8 kf = *reinterpret_cast<const short8*>(
                        &Ks[(kb * 32 + r) * KSTR + ks * 16 + hi * 8]);
                    a = __builtin_amdgcn_mfma_f32_32x32x16_bf16(kf, qf[ks], a, 0, 0, 0);
                }
                sc[kb] = a;
            }
        }

        // ---- mask + online softmax (lane owns q-row tq) ----
        float cmax = -INFINITY;
        #pragma unroll
        for (int kb = 0; kb < 4; ++kb) {
            if (kb < nkb) {
                #pragma unroll
                for (int reg = 0; reg < 16; ++reg) {
                    int key = kb * 32 + (reg & 3) + 8 * (reg >> 2) + 4 * hi;
                    float s = sc[kb][reg];
                    if (kbase + key > tq || msk[key] == 0) s = NEG_INF;
                    sc[kb][reg] = s;
                    cmax = fmaxf(cmax, s);
                }
            }
        }
        cmax = fmaxf(cmax, __shfl_xor(cmax, 32));
        const float m_new  = fmaxf(m, cmax);
        const float scalef = __expf(m - m_new);   // exp(-inf)=0 first chunk
        float csum = 0.f;
        #pragma unroll
        for (int kb = 0; kb < 4; ++kb) {
            if (kb < nkb) {
                #pragma unroll
                for (int reg = 0; reg < 16; ++reg) {
                    float p = __expf(sc[kb][reg] - m_new);
                    sc[kb][reg] = p;
                    csum += p;
                }
            }
        }
        csum += __shfl_xor(csum, 32);
        lsum = lsum * scalef + csum;
        m = m_new;

        // rescale O: acc rows are q = (reg&3)+8*(reg>>2)+4*hi; scale lives in lane q
        #pragma unroll
        for (int reg = 0; reg < 16; ++reg) {
            const float f = __shfl(scalef, (reg & 3) + 8 * (reg >> 2) + 4 * hi);
            accO[0][reg] *= f;
            accO[1][reg] *= f;
        }

        // ---- PV: build P bf16 A-frags in-register, accumulate O += P*V ----
        #pragma unroll
        for (int kb = 0; kb < 4; ++kb) {
            if (kb < nkb) {
                unsigned int pk[8];
                #pragma unroll
                for (int j = 0; j < 8; ++j)
                    pk[j] = bfpack(sc[kb][2 * j], sc[kb][2 * j + 1]);
                #pragma unroll
                for (int hs = 0; hs < 2; ++hs) {
                    const unsigned int p01 = pk[hs * 4 + 0], p23 = pk[hs * 4 + 1];
                    const unsigned int p45 = pk[hs * 4 + 2], p67 = pk[hs * 4 + 3];
                    const unsigned int sendA = hi ? p01 : p45;
                    const unsigned int sendB = hi ? p23 : p67;
                    const unsigned int recvA = (unsigned int)__shfl_xor((int)sendA, 32);
                    const unsigned int recvB = (unsigned int)__shfl_xor((int)sendB, 32);
                    union { unsigned int u[4]; short8 s8; } aw;
                    aw.u[0] = hi ? recvA : p01;   // keys base+0,1  (hi=1: 8,9)
                    aw.u[1] = hi ? recvB : p23;   // keys base+2,3  (hi=1: 10,11)
                    aw.u[2] = hi ? p45 : recvA;   // keys base+4,5  (hi=1: 12,13)
                    aw.u[3] = hi ? p67 : recvB;   // keys base+6,7  (hi=1: 14,15)
                    const int kcol = kb * 32 + hs * 16 + hi * 8;
                    #pragma unroll
                    for (int tile = 0; tile < 2; ++tile) {
                        short8 vb = *reinterpret_cast<const short8*>(
                            &Vt[(r + 32 * tile) * VSTR + kcol]);
                        accO[tile] = __builtin_amdgcn_mfma_f32_32x32x16_bf16(
                            aw.s8, vb, accO[tile], 0, 0, 0);
                    }
                }
            }
        }
    }

    // ---- epilogue: O rows are q=(reg&3)+8*(reg>>2)+4*hi, cols h=r+32*tile ----
    const float invl = 1.f / lsum;
    #pragma unroll
    for (int reg = 0; reg < 16; ++reg) {
        const int qrow = (reg & 3) + 8 * (reg >> 2) + 4 * hi;
        const float f = __shfl(invl, qrow);
        float* op = &out[((size_t)b * T + t0w + qrow) * H];
        op[r]      = accO[0][reg] * f;
        op[r + 32] = accO[1][reg] * f;
    }
}

// ---------------------------------------------------------------------------
extern "C" void kernel_launch(void* const* d_in, const int* in_sizes, int n_in,
                              void* d_out, int out_size, void* d_ws, size_t ws_size,
                              hipStream_t stream) {
    const float* x         = (const float*)d_in[0];
    const int*   attn_mask = (const int*)d_in[1];
    const float* Wk        = (const float*)d_in[2];
    const float* Wq        = (const float*)d_in[3];
    const float* Wv        = (const float*)d_in[4];
    float* out = (float*)d_out;

    unsigned short* qbf = (unsigned short*)d_ws;
    unsigned short* kbf = qbf + (size_t)B * T * H;
    unsigned short* vT  = kbf + (size_t)B * T * H;

    proj_gemm<<<(B * T) / PBM, 256, 0, stream>>>(x, Wq, Wk, Wv, qbf, kbf, vT);
    attn_mfma<<<B * (T / QB), 256, 0, stream>>>(qbf, kbf, vT, attn_mask, out);
}

// Round 4
// 67.088 us; speedup vs baseline: 8.7294x; 1.5261x over previous
//
#include <hip/hip_runtime.h>

#define B 64
#define T 512
#define E 512
#define H 64
#define NEG_INF (-1e30f)

// ---------------- projection GEMM params ----------------
#define PBM 64        // block M tile
#define PBK 64        // K chunk
#define PN 192        // output cols (q|k|v)
#define NCHK (E / PBK)

// ---------------- attention params ----------------
#define QB 128
#define CH 128
#define KSTR 72
#define VSTR 136

using short8 = __attribute__((ext_vector_type(8))) short;
using f32x16 = __attribute__((ext_vector_type(16))) float;

// float -> bf16 bits, round-to-nearest-even
__device__ __forceinline__ unsigned short f2bf(float f) {
    unsigned int u = __float_as_uint(f);
    u += 0x7fffu + ((u >> 16) & 1u);
    return (unsigned short)(u >> 16);
}
__device__ __forceinline__ unsigned int bfpack(float lo, float hi) {
    return ((unsigned int)f2bf(hi) << 16) | (unsigned int)f2bf(lo);
}
// async global->LDS, 16B per lane; l must be wave-uniform
__device__ __forceinline__ void async_copy16(const void* g, void* l) {
    __builtin_amdgcn_global_load_lds(
        (const __attribute__((address_space(1))) unsigned int*)g,
        (__attribute__((address_space(3))) unsigned int*)l, 16, 0, 0);
}

// ---------------------------------------------------------------------------
// Kernel 0: one-time W prep.  Emits WT_swz: for each k-chunk c (8 chunks),
// a contiguous 24 KB block that is the exact LDS image proj_gemm wants:
// linear byte a (row=a>>7, cb=a&127) holds W_seg[c*64 + ((cb^((row&7)<<4))>>1)][row&63]
// i.e. the XOR-swizzle is pre-applied so staging is a straight memcpy.
// ---------------------------------------------------------------------------
__global__ __launch_bounds__(256) void prep_wt(
    const float* __restrict__ Wq, const float* __restrict__ Wk,
    const float* __restrict__ Wv, unsigned short* __restrict__ WT_swz)
{
    const int i = blockIdx.x * 256 + threadIdx.x;    // 0 .. 98303
    const int c   = i / (PN * 64);
    const int rem = i - c * (PN * 64);
    const int row = rem >> 6;                        // 0..191
    const int s   = rem & 63;                        // short within row
    const int klocal = s ^ ((row & 7) << 3);         // pre-applied swizzle
    const int k   = c * 64 + klocal;
    const int seg = row >> 6, hh = row & 63;
    const float* W = (seg == 0) ? Wq : (seg == 1) ? Wk : Wv;
    WT_swz[i] = f2bf(W[(size_t)k * H + hh]);
}

// ---------------------------------------------------------------------------
// Kernel 1: fused q/k/v projection GEMM.
// A = x (32768x512) -> bf16 staged in Xs (XOR-swizzled, stride 128B).
// B = WT_swz staged via global_load_lds (contiguous, swizzle pre-baked).
// Block 64x192, 4 waves (2 row-groups x 2 col-groups), 32x96 per wave,
// mfma_f32_32x32x16_bf16.  Epilogue: q bf16 (pre-scaled 1/8), k bf16,
// v bf16 transposed vT[b][h][t].
// ---------------------------------------------------------------------------
__global__ __launch_bounds__(256) void proj_gemm(
    const float* __restrict__ x,
    const unsigned short* __restrict__ WT_swz,
    unsigned short* __restrict__ qbf, unsigned short* __restrict__ kbf,
    unsigned short* __restrict__ vT)
{
    __shared__ unsigned short Xs[PBM * 64];   // 8 KB, swizzled
    __shared__ unsigned short Ws[PN * 64];    // 24 KB, swizzled

    const int tid  = threadIdx.x;
    const int wid  = tid >> 6;
    const int lane = tid & 63;
    const int hi   = lane >> 5;
    const int r    = lane & 31;
    const int row0 = blockIdx.x * PBM;

    const int mrow  = (wid >> 1) * 32 + r;
    const int cbase = (wid & 1) * 96;

    const int aBase = mrow * 128;             // LDS byte base of A row
    const int aXor  = (mrow & 7) << 4;
    int bBase[3], bXor[3];
    #pragma unroll
    for (int nt = 0; nt < 3; ++nt) {
        const int col = cbase + nt * 32 + r;
        bBase[nt] = col * 128;
        bXor[nt]  = (col & 7) << 4;
    }

    f32x16 acc[3] = {};

    for (int c = 0; c < NCHK; ++c) {
        const int kc = c * PBK;
        __syncthreads();                      // prev compute done with LDS

        // ---- stage Ws: straight async copy of the pre-swizzled chunk ----
        {
            const unsigned short* gw = WT_swz + (size_t)c * (PN * 64);
            #pragma unroll
            for (int p = 0; p < 6; ++p) {
                const int u = p * 256 + wid * 64 + lane;     // 16B unit
                async_copy16(gw + u * 8,
                             (char*)Ws + (p * 256 + wid * 64) * 16);
            }
        }
        // ---- stage Xs: f32->bf16, XOR-swizzled 16B writes ----
        #pragma unroll
        for (int p = 0; p < 2; ++p) {
            const int u  = p * 256 + tid;     // 16B unit: 64 rows x 8
            const int rr = u >> 3, s16 = u & 7;
            const float4* src = reinterpret_cast<const float4*>(
                &x[(size_t)(row0 + rr) * E + kc + s16 * 8]);
            const float4 a0 = src[0], a1 = src[1];
            union { unsigned short us[8]; short8 v; } pk;
            pk.us[0] = f2bf(a0.x); pk.us[1] = f2bf(a0.y);
            pk.us[2] = f2bf(a0.z); pk.us[3] = f2bf(a0.w);
            pk.us[4] = f2bf(a1.x); pk.us[5] = f2bf(a1.y);
            pk.us[6] = f2bf(a1.z); pk.us[7] = f2bf(a1.w);
            const int cb = (s16 * 16) ^ ((rr & 7) << 4);
            *reinterpret_cast<short8*>((char*)Xs + rr * 128 + cb) = pk.v;
        }
        __syncthreads();                      // drains vmcnt (global_load_lds)

        // ---- MFMA: 4 K-steps of 16 ----
        #pragma unroll
        for (int ks = 0; ks < 4; ++ks) {
            const int koff = ks * 32 + hi * 16;   // byte col within row
            const short8 a = *reinterpret_cast<const short8*>(
                (const char*)Xs + aBase + (koff ^ aXor));
            #pragma unroll
            for (int nt = 0; nt < 3; ++nt) {
                const short8 b = *reinterpret_cast<const short8*>(
                    (const char*)Ws + bBase[nt] + (koff ^ bXor[nt]));
                acc[nt] = __builtin_amdgcn_mfma_f32_32x32x16_bf16(a, b, acc[nt], 0, 0, 0);
            }
        }
    }

    // ---- epilogue: C/D layout col=lane&31, row=(reg&3)+8*(reg>>2)+4*hi ----
    #pragma unroll
    for (int nt = 0; nt < 3; ++nt) {
        const int gc  = cbase + nt * 32 + r;
        const int seg = gc >> 6;
        const int hh  = gc & 63;
        #pragma unroll
        for (int reg = 0; reg < 16; ++reg) {
            const int drow = (reg & 3) + 8 * (reg >> 2) + 4 * hi;
            const int grow = row0 + (wid >> 1) * 32 + drow;
            const float val = acc[nt][reg];
            if (seg == 0) {
                qbf[(size_t)grow * H + hh] = f2bf(val * 0.125f);
            } else if (seg == 1) {
                kbf[(size_t)grow * H + hh] = f2bf(val);
            } else {
                const int bb = grow >> 9, tt = grow & 511;
                vT[((size_t)bb * H + hh) * T + tt] = f2bf(val);
            }
        }
    }
}

// ---------------------------------------------------------------------------
// Kernel 2: MFMA flash attention (unchanged from round 3).
// ---------------------------------------------------------------------------
__global__ __launch_bounds__(256) void attn_mfma(
    const unsigned short* __restrict__ qbf,
    const unsigned short* __restrict__ kbf,
    const unsigned short* __restrict__ vT,
    const int* __restrict__ attn_mask,
    float* __restrict__ out)
{
    __shared__ unsigned short Ks[CH * KSTR];
    __shared__ unsigned short Vt[H * VSTR];
    __shared__ int msk[CH];

    const int tid  = threadIdx.x;
    const int wid  = tid >> 6;
    const int lane = tid & 63;
    const int hi   = lane >> 5;
    const int r    = lane & 31;

    const int b     = blockIdx.x >> 2;
    const int strip = blockIdx.x & 3;
    const int t0w   = strip * QB + wid * 32;
    const int tq    = t0w + r;

    short8 qf[4];
    #pragma unroll
    for (int ks = 0; ks < 4; ++ks)
        qf[ks] = *reinterpret_cast<const short8*>(
            &qbf[((size_t)b * T + t0w + r) * H + ks * 16 + hi * 8]);

    f32x16 accO[2] = {};
    float m = -INFINITY, lsum = 0.f;

    const int nchunk = strip + 1;
    for (int c = 0; c < nchunk; ++c) {
        const int kbase = c * CH;
        __syncthreads();
        #pragma unroll
        for (int p = 0; p < 4; ++p) {
            int u = tid + p * 256;
            int row = u >> 3, o8 = (u & 7) * 8;
            *reinterpret_cast<short8*>(&Ks[row * KSTR + o8]) =
                *reinterpret_cast<const short8*>(
                    &kbf[((size_t)b * T + kbase + row) * H + o8]);
        }
        #pragma unroll
        for (int p = 0; p < 4; ++p) {
            int u = tid + p * 256;
            int h = u >> 4, j8 = (u & 15) * 8;
            *reinterpret_cast<short8*>(&Vt[h * VSTR + j8]) =
                *reinterpret_cast<const short8*>(
                    &vT[((size_t)b * H + h) * T + kbase + j8]);
        }
        if (tid < CH) msk[tid] = attn_mask[b * T + kbase + tid];
        __syncthreads();

        const int nkb = min(4, ((t0w + 31 - kbase) >> 5) + 1);

        f32x16 sc[4];
        #pragma unroll
        for (int kb = 0; kb < 4; ++kb) {
            if (kb < nkb) {
                f32x16 a = {};
                #pragma unroll
                for (int ks = 0; ks < 4; ++ks) {
                    short8 kf = *reinterpret_cast<const short8*>(
                        &Ks[(kb * 32 + r) * KSTR + ks * 16 + hi * 8]);
                    a = __builtin_amdgcn_mfma_f32_32x32x16_bf16(kf, qf[ks], a, 0, 0, 0);
                }
                sc[kb] = a;
            }
        }

        float cmax = -INFINITY;
        #pragma unroll
        for (int kb = 0; kb < 4; ++kb) {
            if (kb < nkb) {
                #pragma unroll
                for (int reg = 0; reg < 16; ++reg) {
                    int key = kb * 32 + (reg & 3) + 8 * (reg >> 2) + 4 * hi;
                    float s = sc[kb][reg];
                    if (kbase + key > tq || msk[key] == 0) s = NEG_INF;
                    sc[kb][reg] = s;
                    cmax = fmaxf(cmax, s);
                }
            }
        }
        cmax = fmaxf(cmax, __shfl_xor(cmax, 32));
        const float m_new  = fmaxf(m, cmax);
        const float scalef = __expf(m - m_new);
        float csum = 0.f;
        #pragma unroll
        for (int kb = 0; kb < 4; ++kb) {
            if (kb < nkb) {
                #pragma unroll
                for (int reg = 0; reg < 16; ++reg) {
                    float p = __expf(sc[kb][reg] - m_new);
                    sc[kb][reg] = p;
                    csum += p;
                }
            }
        }
        csum += __shfl_xor(csum, 32);
        lsum = lsum * scalef + csum;
        m = m_new;

        #pragma unroll
        for (int reg = 0; reg < 16; ++reg) {
            const float f = __shfl(scalef, (reg & 3) + 8 * (reg >> 2) + 4 * hi);
            accO[0][reg] *= f;
            accO[1][reg] *= f;
        }

        #pragma unroll
        for (int kb = 0; kb < 4; ++kb) {
            if (kb < nkb) {
                unsigned int pk[8];
                #pragma unroll
                for (int j = 0; j < 8; ++j)
                    pk[j] = bfpack(sc[kb][2 * j], sc[kb][2 * j + 1]);
                #pragma unroll
                for (int hs = 0; hs < 2; ++hs) {
                    const unsigned int p01 = pk[hs * 4 + 0], p23 = pk[hs * 4 + 1];
                    const unsigned int p45 = pk[hs * 4 + 2], p67 = pk[hs * 4 + 3];
                    const unsigned int sendA = hi ? p01 : p45;
                    const unsigned int sendB = hi ? p23 : p67;
                    const unsigned int recvA = (unsigned int)__shfl_xor((int)sendA, 32);
                    const unsigned int recvB = (unsigned int)__shfl_xor((int)sendB, 32);
                    union { unsigned int u[4]; short8 s8; } aw;
                    aw.u[0] = hi ? recvA : p01;
                    aw.u[1] = hi ? recvB : p23;
                    aw.u[2] = hi ? p45 : recvA;
                    aw.u[3] = hi ? p67 : recvB;
                    const int kcol = kb * 32 + hs * 16 + hi * 8;
                    #pragma unroll
                    for (int tile = 0; tile < 2; ++tile) {
                        short8 vb = *reinterpret_cast<const short8*>(
                            &Vt[(r + 32 * tile) * VSTR + kcol]);
                        accO[tile] = __builtin_amdgcn_mfma_f32_32x32x16_bf16(
                            aw.s8, vb, accO[tile], 0, 0, 0);
                    }
                }
            }
        }
    }

    const float invl = 1.f / lsum;
    #pragma unroll
    for (int reg = 0; reg < 16; ++reg) {
        const int qrow = (reg & 3) + 8 * (reg >> 2) + 4 * hi;
        const float f = __shfl(invl, qrow);
        float* op = &out[((size_t)b * T + t0w + qrow) * H];
        op[r]      = accO[0][reg] * f;
        op[r + 32] = accO[1][reg] * f;
    }
}

// ---------------------------------------------------------------------------
extern "C" void kernel_launch(void* const* d_in, const int* in_sizes, int n_in,
                              void* d_out, int out_size, void* d_ws, size_t ws_size,
                              hipStream_t stream) {
    const float* x         = (const float*)d_in[0];
    const int*   attn_mask = (const int*)d_in[1];
    const float* Wk        = (const float*)d_in[2];
    const float* Wq        = (const float*)d_in[3];
    const float* Wv        = (const float*)d_in[4];
    float* out = (float*)d_out;

    unsigned short* qbf    = (unsigned short*)d_ws;
    unsigned short* kbf    = qbf + (size_t)B * T * H;
    unsigned short* vT     = kbf + (size_t)B * T * H;
    unsigned short* WT_swz = vT  + (size_t)B * T * H;   // 192 KB

    prep_wt<<<(PN * E) / 256, 256, 0, stream>>>(Wq, Wk, Wv, WT_swz);
    proj_gemm<<<(B * T) / PBM, 256, 0, stream>>>(x, WT_swz, qbf, kbf, vT);
    attn_mfma<<<B * (T / QB), 256, 0, stream>>>(qbf, kbf, vT, attn_mask, out);
}

// Round 5
// 65.107 us; speedup vs baseline: 8.9950x; 1.0304x over previous
//
#include <hip/hip_runtime.h>

#define B 64
#define T 512
#define E 512
#define H 64
#define NEG_INF (-1e30f)

// ---------------- projection GEMM params ----------------
#define PBM 64        // block M tile
#define PBK 64        // K chunk
#define PN 192        // output cols (q|k|v)
#define NCHK (E / PBK)

// ---------------- attention params ----------------
#define QB 128        // q rows per strip (4 waves x 32)
#define CH 128        // keys per chunk
#define KSTR 72       // Ks LDS row stride (bf16), 144B
#define VSTR 136      // Vt LDS row stride (bf16), 272B
#define NUNIT 10      // causal (strip,chunk) pairs per batch: 1+2+3+4

using short8 = __attribute__((ext_vector_type(8))) short;
using f32x16 = __attribute__((ext_vector_type(16))) float;

// float -> bf16 bits, round-to-nearest-even
__device__ __forceinline__ unsigned short f2bf(float f) {
    unsigned int u = __float_as_uint(f);
    u += 0x7fffu + ((u >> 16) & 1u);
    return (unsigned short)(u >> 16);
}
__device__ __forceinline__ float bf2f(unsigned short s) {
    return __uint_as_float((unsigned int)s << 16);
}
__device__ __forceinline__ unsigned int bfpack(float lo, float hi) {
    return ((unsigned int)f2bf(hi) << 16) | (unsigned int)f2bf(lo);
}
// async global->LDS, 16B per lane; l must be wave-uniform
__device__ __forceinline__ void async_copy16(const void* g, void* l) {
    __builtin_amdgcn_global_load_lds(
        (const __attribute__((address_space(1))) unsigned int*)g,
        (__attribute__((address_space(3))) unsigned int*)l, 16, 0, 0);
}

// ---------------------------------------------------------------------------
// Kernel 0: one-time W prep (unchanged from round 4).
// ---------------------------------------------------------------------------
__global__ __launch_bounds__(256) void prep_wt(
    const float* __restrict__ Wq, const float* __restrict__ Wk,
    const float* __restrict__ Wv, unsigned short* __restrict__ WT_swz)
{
    const int i = blockIdx.x * 256 + threadIdx.x;
    const int c   = i / (PN * 64);
    const int rem = i - c * (PN * 64);
    const int row = rem >> 6;
    const int s   = rem & 63;
    const int klocal = s ^ ((row & 7) << 3);
    const int k   = c * 64 + klocal;
    const int seg = row >> 6, hh = row & 63;
    const float* W = (seg == 0) ? Wq : (seg == 1) ? Wk : Wv;
    WT_swz[i] = f2bf(W[(size_t)k * H + hh]);
}

// ---------------------------------------------------------------------------
// Kernel 1: fused q/k/v projection GEMM (unchanged from round 4).
// ---------------------------------------------------------------------------
__global__ __launch_bounds__(256) void proj_gemm(
    const float* __restrict__ x,
    const unsigned short* __restrict__ WT_swz,
    unsigned short* __restrict__ qbf, unsigned short* __restrict__ kbf,
    unsigned short* __restrict__ vT)
{
    __shared__ unsigned short Xs[PBM * 64];
    __shared__ unsigned short Ws[PN * 64];

    const int tid  = threadIdx.x;
    const int wid  = tid >> 6;
    const int lane = tid & 63;
    const int hi   = lane >> 5;
    const int r    = lane & 31;
    const int row0 = blockIdx.x * PBM;

    const int mrow  = (wid >> 1) * 32 + r;
    const int cbase = (wid & 1) * 96;

    const int aBase = mrow * 128;
    const int aXor  = (mrow & 7) << 4;
    int bBase[3], bXor[3];
    #pragma unroll
    for (int nt = 0; nt < 3; ++nt) {
        const int col = cbase + nt * 32 + r;
        bBase[nt] = col * 128;
        bXor[nt]  = (col & 7) << 4;
    }

    f32x16 acc[3] = {};

    for (int c = 0; c < NCHK; ++c) {
        const int kc = c * PBK;
        __syncthreads();

        {
            const unsigned short* gw = WT_swz + (size_t)c * (PN * 64);
            #pragma unroll
            for (int p = 0; p < 6; ++p) {
                const int u = p * 256 + wid * 64 + lane;
                async_copy16(gw + u * 8,
                             (char*)Ws + (p * 256 + wid * 64) * 16);
            }
        }
        #pragma unroll
        for (int p = 0; p < 2; ++p) {
            const int u  = p * 256 + tid;
            const int rr = u >> 3, s16 = u & 7;
            const float4* src = reinterpret_cast<const float4*>(
                &x[(size_t)(row0 + rr) * E + kc + s16 * 8]);
            const float4 a0 = src[0], a1 = src[1];
            union { unsigned short us[8]; short8 v; } pk;
            pk.us[0] = f2bf(a0.x); pk.us[1] = f2bf(a0.y);
            pk.us[2] = f2bf(a0.z); pk.us[3] = f2bf(a0.w);
            pk.us[4] = f2bf(a1.x); pk.us[5] = f2bf(a1.y);
            pk.us[6] = f2bf(a1.z); pk.us[7] = f2bf(a1.w);
            const int cb = (s16 * 16) ^ ((rr & 7) << 4);
            *reinterpret_cast<short8*>((char*)Xs + rr * 128 + cb) = pk.v;
        }
        __syncthreads();

        #pragma unroll
        for (int ks = 0; ks < 4; ++ks) {
            const int koff = ks * 32 + hi * 16;
            const short8 a = *reinterpret_cast<const short8*>(
                (const char*)Xs + aBase + (koff ^ aXor));
            #pragma unroll
            for (int nt = 0; nt < 3; ++nt) {
                const short8 b = *reinterpret_cast<const short8*>(
                    (const char*)Ws + bBase[nt] + (koff ^ bXor[nt]));
                acc[nt] = __builtin_amdgcn_mfma_f32_32x32x16_bf16(a, b, acc[nt], 0, 0, 0);
            }
        }
    }

    #pragma unroll
    for (int nt = 0; nt < 3; ++nt) {
        const int gc  = cbase + nt * 32 + r;
        const int seg = gc >> 6;
        const int hh  = gc & 63;
        #pragma unroll
        for (int reg = 0; reg < 16; ++reg) {
            const int drow = (reg & 3) + 8 * (reg >> 2) + 4 * hi;
            const int grow = row0 + (wid >> 1) * 32 + drow;
            const float val = acc[nt][reg];
            if (seg == 0) {
                qbf[(size_t)grow * H + hh] = f2bf(val * 0.125f);
            } else if (seg == 1) {
                kbf[(size_t)grow * H + hh] = f2bf(val);
            } else {
                const int bb = grow >> 9, tt = grow & 511;
                vT[((size_t)bb * H + hh) * T + tt] = f2bf(val);
            }
        }
    }
}

// ---------------------------------------------------------------------------
// Kernel 2a: split-K attention partials.  One block per (batch, strip, chunk)
// causal unit -> 640 balanced blocks (~2.5/CU, 2-3 waves/SIMD).  Each block:
// stage one 128-key chunk, swapped QK^T, LOCAL softmax (chunk max/sum, no
// online state), PV, write unnormalized partial O (bf16) + per-row m,l (f32).
// ---------------------------------------------------------------------------
__global__ __launch_bounds__(256) void attn_part(
    const unsigned short* __restrict__ qbf,
    const unsigned short* __restrict__ kbf,
    const unsigned short* __restrict__ vT,
    const int* __restrict__ attn_mask,
    unsigned short* __restrict__ O_part,
    float* __restrict__ m_part, float* __restrict__ l_part)
{
    __shared__ unsigned short Ks[CH * KSTR];
    __shared__ unsigned short Vt[H * VSTR];
    __shared__ int msk[CH];

    const int tid  = threadIdx.x;
    const int wid  = tid >> 6;
    const int lane = tid & 63;
    const int hi   = lane >> 5;
    const int r    = lane & 31;

    const int u = blockIdx.x;
    const int b = u / NUNIT;
    const int t = u - b * NUNIT;
    int strip, chunk;                       // tri index: 0;1,2;3..5;6..9
    if (t == 0)      { strip = 0; chunk = 0; }
    else if (t < 3)  { strip = 1; chunk = t - 1; }
    else if (t < 6)  { strip = 2; chunk = t - 3; }
    else             { strip = 3; chunk = t - 6; }

    const int t0w   = strip * QB + wid * 32;
    const int tq    = t0w + r;
    const int kbase = chunk * CH;

    // Q fragments (pre-scaled by 1/8 in proj)
    short8 qf[4];
    #pragma unroll
    for (int ks = 0; ks < 4; ++ks)
        qf[ks] = *reinterpret_cast<const short8*>(
            &qbf[((size_t)b * T + t0w + r) * H + ks * 16 + hi * 8]);

    // stage K chunk, V^T chunk, mask
    #pragma unroll
    for (int p = 0; p < 4; ++p) {
        int uu = tid + p * 256;
        int row = uu >> 3, o8 = (uu & 7) * 8;
        *reinterpret_cast<short8*>(&Ks[row * KSTR + o8]) =
            *reinterpret_cast<const short8*>(
                &kbf[((size_t)b * T + kbase + row) * H + o8]);
    }
    #pragma unroll
    for (int p = 0; p < 4; ++p) {
        int uu = tid + p * 256;
        int h = uu >> 4, j8 = (uu & 15) * 8;
        *reinterpret_cast<short8*>(&Vt[h * VSTR + j8]) =
            *reinterpret_cast<const short8*>(
                &vT[((size_t)b * H + h) * T + kbase + j8]);
    }
    if (tid < CH) msk[tid] = attn_mask[b * T + kbase + tid];
    __syncthreads();

    // wave-uniform count of 32-key blocks (off-diagonal chunks: always 4)
    const int nkb = min(4, ((t0w + 31 - kbase) >> 5) + 1);

    // ---- QK^T swapped: col=q(lane&31), row=key-in-block ----
    f32x16 sc[4];
    #pragma unroll
    for (int kb = 0; kb < 4; ++kb) {
        if (kb < nkb) {
            f32x16 a = {};
            #pragma unroll
            for (int ks = 0; ks < 4; ++ks) {
                short8 kf = *reinterpret_cast<const short8*>(
                    &Ks[(kb * 32 + r) * KSTR + ks * 16 + hi * 8]);
                a = __builtin_amdgcn_mfma_f32_32x32x16_bf16(kf, qf[ks], a, 0, 0, 0);
            }
            sc[kb] = a;
        }
    }

    // ---- mask + local softmax ----
    float cmax = -INFINITY;
    #pragma unroll
    for (int kb = 0; kb < 4; ++kb) {
        if (kb < nkb) {
            #pragma unroll
            for (int reg = 0; reg < 16; ++reg) {
                int key = kb * 32 + (reg & 3) + 8 * (reg >> 2) + 4 * hi;
                float s = sc[kb][reg];
                if (kbase + key > tq || msk[key] == 0) s = NEG_INF;
                sc[kb][reg] = s;
                cmax = fmaxf(cmax, s);
            }
        }
    }
    cmax = fmaxf(cmax, __shfl_xor(cmax, 32));
    float csum = 0.f;
    #pragma unroll
    for (int kb = 0; kb < 4; ++kb) {
        if (kb < nkb) {
            #pragma unroll
            for (int reg = 0; reg < 16; ++reg) {
                float p = __expf(sc[kb][reg] - cmax);
                sc[kb][reg] = p;
                csum += p;
            }
        }
    }
    csum += __shfl_xor(csum, 32);

    // ---- PV ----
    f32x16 accO[2] = {};
    #pragma unroll
    for (int kb = 0; kb < 4; ++kb) {
        if (kb < nkb) {
            unsigned int pk[8];
            #pragma unroll
            for (int j = 0; j < 8; ++j)
                pk[j] = bfpack(sc[kb][2 * j], sc[kb][2 * j + 1]);
            #pragma unroll
            for (int hs = 0; hs < 2; ++hs) {
                const unsigned int p01 = pk[hs * 4 + 0], p23 = pk[hs * 4 + 1];
                const unsigned int p45 = pk[hs * 4 + 2], p67 = pk[hs * 4 + 3];
                const unsigned int sendA = hi ? p01 : p45;
                const unsigned int sendB = hi ? p23 : p67;
                const unsigned int recvA = (unsigned int)__shfl_xor((int)sendA, 32);
                const unsigned int recvB = (unsigned int)__shfl_xor((int)sendB, 32);
                union { unsigned int uu[4]; short8 s8; } aw;
                aw.uu[0] = hi ? recvA : p01;
                aw.uu[1] = hi ? recvB : p23;
                aw.uu[2] = hi ? p45 : recvA;
                aw.uu[3] = hi ? p67 : recvB;
                const int kcol = kb * 32 + hs * 16 + hi * 8;
                #pragma unroll
                for (int tile = 0; tile < 2; ++tile) {
                    short8 vb = *reinterpret_cast<const short8*>(
                        &Vt[(r + 32 * tile) * VSTR + kcol]);
                    accO[tile] = __builtin_amdgcn_mfma_f32_32x32x16_bf16(
                        aw.s8, vb, accO[tile], 0, 0, 0);
                }
            }
        }
    }

    // ---- write partials: O' bf16, m/l f32 ----
    #pragma unroll
    for (int reg = 0; reg < 16; ++reg) {
        const int qrow = (reg & 3) + 8 * (reg >> 2) + 4 * hi;
        unsigned short* op = &O_part[((size_t)u * QB + wid * 32 + qrow) * H];
        op[r]      = f2bf(accO[0][reg]);
        op[r + 32] = f2bf(accO[1][reg]);
    }
    if (hi == 0) {
        m_part[u * QB + wid * 32 + r] = cmax;
        l_part[u * QB + wid * 32 + r] = csum;
    }
}

// ---------------------------------------------------------------------------
// Kernel 2b: combine partials.  One block per (batch, strip); merges the
// strip's (strip+1) chunk partials and normalizes.  Fully coalesced:
// short8 partial reads, float4 output stores.
// ---------------------------------------------------------------------------
__global__ __launch_bounds__(256) void attn_comb(
    const unsigned short* __restrict__ O_part,
    const float* __restrict__ m_part, const float* __restrict__ l_part,
    float* __restrict__ out)
{
    const int b     = blockIdx.x >> 2;
    const int strip = blockIdx.x & 3;
    const int nc    = strip + 1;
    const int ubase = b * NUNIT + ((strip * (strip + 1)) >> 1);
    const int tid   = threadIdx.x;
    const int col8  = (tid & 7) * 8;

    #pragma unroll
    for (int pass = 0; pass < 4; ++pass) {
        const int row = pass * 32 + (tid >> 3);

        float mstar = -INFINITY;
        float mi[4], li[4];
        #pragma unroll
        for (int c = 0; c < 4; ++c) {
            if (c < nc) {
                mi[c] = m_part[(ubase + c) * QB + row];
                li[c] = l_part[(ubase + c) * QB + row];
                mstar = fmaxf(mstar, mi[c]);
            }
        }
        float lsum = 0.f, fc[4];
        #pragma unroll
        for (int c = 0; c < 4; ++c) {
            if (c < nc) {
                fc[c] = __expf(mi[c] - mstar);
                lsum += fc[c] * li[c];
            }
        }
        const float inv = 1.f / lsum;

        float acc[8] = {};
        #pragma unroll
        for (int c = 0; c < 4; ++c) {
            if (c < nc) {
                union { short8 v; unsigned short us[8]; } o;
                o.v = *reinterpret_cast<const short8*>(
                    &O_part[((size_t)(ubase + c) * QB + row) * H + col8]);
                #pragma unroll
                for (int j = 0; j < 8; ++j)
                    acc[j] += fc[c] * bf2f(o.us[j]);
            }
        }

        float* op = &out[((size_t)b * T + strip * QB + row) * H + col8];
        float4 lo4 = { acc[0] * inv, acc[1] * inv, acc[2] * inv, acc[3] * inv };
        float4 hi4 = { acc[4] * inv, acc[5] * inv, acc[6] * inv, acc[7] * inv };
        *reinterpret_cast<float4*>(op)     = lo4;
        *reinterpret_cast<float4*>(op + 4) = hi4;
    }
}

// ---------------------------------------------------------------------------
extern "C" void kernel_launch(void* const* d_in, const int* in_sizes, int n_in,
                              void* d_out, int out_size, void* d_ws, size_t ws_size,
                              hipStream_t stream) {
    const float* x         = (const float*)d_in[0];
    const int*   attn_mask = (const int*)d_in[1];
    const float* Wk        = (const float*)d_in[2];
    const float* Wq        = (const float*)d_in[3];
    const float* Wv        = (const float*)d_in[4];
    float* out = (float*)d_out;

    unsigned short* qbf    = (unsigned short*)d_ws;                  // 4 MB
    unsigned short* kbf    = qbf + (size_t)B * T * H;                // 4 MB
    unsigned short* vT     = kbf + (size_t)B * T * H;                // 4 MB
    unsigned short* WT_swz = vT  + (size_t)B * T * H;                // 192 KB
    unsigned short* O_part = WT_swz + (size_t)PN * E;                // 10.5 MB
    float*          m_part = (float*)(O_part + (size_t)B * NUNIT * QB * H); // 328 KB
    float*          l_part = m_part + (size_t)B * NUNIT * QB;        // 328 KB

    prep_wt<<<(PN * E) / 256, 256, 0, stream>>>(Wq, Wk, Wv, WT_swz);
    proj_gemm<<<(B * T) / PBM, 256, 0, stream>>>(x, WT_swz, qbf, kbf, vT);
    attn_part<<<B * NUNIT, 256, 0, stream>>>(qbf, kbf, vT, attn_mask,
                                             O_part, m_part, l_part);
    attn_comb<<<B * 4, 256, 0, stream>>>(O_part, m_part, l_part, out);
}

// Round 6
// 62.475 us; speedup vs baseline: 9.3738x; 1.0421x over previous
//
#include <hip/hip_runtime.h>

#define B 64
#define T 512
#define E 512
#define H 64
#define NEG_INF (-1e30f)

// ---------------- projection GEMM params ----------------
#define PBM 64        // block M tile
#define PBK 64        // K chunk
#define PN 192        // output cols (q|k|v)
#define NCHK (E / PBK)

// ---------------- attention params ----------------
#define NUNIT 40      // (chunk,strip32) causal units per batch: 16+12+8+4

using short8 = __attribute__((ext_vector_type(8))) short;
using f32x16 = __attribute__((ext_vector_type(16))) float;

// float -> bf16 bits, round-to-nearest-even
__device__ __forceinline__ unsigned short f2bf(float f) {
    unsigned int u = __float_as_uint(f);
    u += 0x7fffu + ((u >> 16) & 1u);
    return (unsigned short)(u >> 16);
}
__device__ __forceinline__ float bf2f(unsigned short s) {
    return __uint_as_float((unsigned int)s << 16);
}
// truncating pack (P in [0,exp-range]; rel err <= 2^-8, fine for P*V)
__device__ __forceinline__ unsigned int bfpack_tr(float lo, float hi) {
    return (__float_as_uint(hi) & 0xffff0000u) | (__float_as_uint(lo) >> 16);
}
// async global->LDS, 16B per lane; LDS base must be wave-uniform
__device__ __forceinline__ void async_copy16(const void* g, void* l) {
    __builtin_amdgcn_global_load_lds(
        (const __attribute__((address_space(1))) unsigned int*)g,
        (__attribute__((address_space(3))) unsigned int*)l, 16, 0, 0);
}

// ---------------------------------------------------------------------------
// Kernel 0: one-time prep.  Blocks 0..383: W -> pre-swizzled bf16 chunks
// (as round 4).  Blocks 384..511: attn_mask -> bitmask words (u32 per 32 keys).
// ---------------------------------------------------------------------------
__global__ __launch_bounds__(256) void prep(
    const float* __restrict__ Wq, const float* __restrict__ Wk,
    const float* __restrict__ Wv, const int* __restrict__ am,
    unsigned short* __restrict__ WT_swz, unsigned int* __restrict__ mbits)
{
    const int bid = blockIdx.x;
    if (bid < 384) {
        const int i = bid * 256 + threadIdx.x;
        const int c   = i / (PN * 64);
        const int rem = i - c * (PN * 64);
        const int row = rem >> 6;
        const int s   = rem & 63;
        const int klocal = s ^ ((row & 7) << 3);
        const int k   = c * 64 + klocal;
        const int seg = row >> 6, hh = row & 63;
        const float* W = (seg == 0) ? Wq : (seg == 1) ? Wk : Wv;
        WT_swz[i] = f2bf(W[(size_t)k * H + hh]);
    } else {
        const int i = (bid - 384) * 256 + threadIdx.x;   // 0..32767
        const unsigned long long bal = __ballot(am[i] != 0);
        const int lane = threadIdx.x & 63;
        if (lane == 0)       mbits[i >> 5] = (unsigned int)bal;
        else if (lane == 32) mbits[i >> 5] = (unsigned int)(bal >> 32);
    }
}

// ---------------------------------------------------------------------------
// Kernel 1: fused q/k/v projection GEMM, 2-phase pipelined double buffer.
// Per chunk: issue next-chunk staging (Ws via global_load_lds, Xs global->reg)
// BEFORE the MFMAs, convert+ds_write after, ONE barrier per chunk.
// ---------------------------------------------------------------------------
__global__ __launch_bounds__(256) void proj_gemm(
    const float* __restrict__ x,
    const unsigned short* __restrict__ WT_swz,
    unsigned short* __restrict__ qbf, unsigned short* __restrict__ kbf,
    unsigned short* __restrict__ vT)
{
    __shared__ unsigned short Xs[2][PBM * 64];   // 2 x 8 KB, swizzled
    __shared__ unsigned short Ws[2][PN * 64];    // 2 x 24 KB, swizzled

    const int tid  = threadIdx.x;
    const int wid  = tid >> 6;
    const int lane = tid & 63;
    const int hi   = lane >> 5;
    const int r    = lane & 31;
    const int row0 = blockIdx.x * PBM;

    const int mrow  = (wid >> 1) * 32 + r;
    const int cbase = (wid & 1) * 96;

    const int aBase = mrow * 128;
    const int aXor  = (mrow & 7) << 4;
    int bBase[3], bXor[3];
    #pragma unroll
    for (int nt = 0; nt < 3; ++nt) {
        const int col = cbase + nt * 32 + r;
        bBase[nt] = col * 128;
        bXor[nt]  = (col & 7) << 4;
    }

    // thread's fixed staging coords
    const int xs_rr[2]  = { tid >> 3, (256 + tid) >> 3 };
    const int xs_s16[2] = { tid & 7, tid & 7 };   // (p*256+tid)&7 == tid&7

    f32x16 acc[3] = {};

    // ---- prologue: stage chunk 0 into buffer 0 ----
    {
        const unsigned short* gw = WT_swz;
        #pragma unroll
        for (int p = 0; p < 6; ++p) {
            const int u = p * 256 + wid * 64 + lane;
            async_copy16(gw + u * 8, (char*)(&Ws[0][0]) + (p * 256 + wid * 64) * 16);
        }
        #pragma unroll
        for (int p = 0; p < 2; ++p) {
            const int rr = xs_rr[p], s16 = xs_s16[p];
            const float4* src = reinterpret_cast<const float4*>(
                &x[(size_t)(row0 + rr) * E + s16 * 8]);
            const float4 a0 = src[0], a1 = src[1];
            union { unsigned short us[8]; short8 v; } pk;
            pk.us[0] = f2bf(a0.x); pk.us[1] = f2bf(a0.y);
            pk.us[2] = f2bf(a0.z); pk.us[3] = f2bf(a0.w);
            pk.us[4] = f2bf(a1.x); pk.us[5] = f2bf(a1.y);
            pk.us[6] = f2bf(a1.z); pk.us[7] = f2bf(a1.w);
            const int cb = (s16 * 16) ^ ((rr & 7) << 4);
            *reinterpret_cast<short8*>((char*)(&Xs[0][0]) + rr * 128 + cb) = pk.v;
        }
        __syncthreads();
    }

    for (int c = 0; c < NCHK; ++c) {
        const int cur = c & 1;
        const bool pre = (c + 1 < NCHK);
        float4 xa[2], xb[2];

        if (pre) {
            // issue next-chunk Ws (async DMA) and Xs global loads NOW
            const unsigned short* gw = WT_swz + (size_t)(c + 1) * (PN * 64);
            #pragma unroll
            for (int p = 0; p < 6; ++p) {
                const int u = p * 256 + wid * 64 + lane;
                async_copy16(gw + u * 8,
                             (char*)(&Ws[cur ^ 1][0]) + (p * 256 + wid * 64) * 16);
            }
            const int kc = (c + 1) * PBK;
            #pragma unroll
            for (int p = 0; p < 2; ++p) {
                const float4* src = reinterpret_cast<const float4*>(
                    &x[(size_t)(row0 + xs_rr[p]) * E + kc + xs_s16[p] * 8]);
                xa[p] = src[0];
                xb[p] = src[1];
            }
        }

        // ---- MFMA on current buffer: 4 K-steps of 16 ----
        #pragma unroll
        for (int ks = 0; ks < 4; ++ks) {
            const int koff = ks * 32 + hi * 16;
            const short8 a = *reinterpret_cast<const short8*>(
                (const char*)(&Xs[cur][0]) + aBase + (koff ^ aXor));
            #pragma unroll
            for (int nt = 0; nt < 3; ++nt) {
                const short8 b = *reinterpret_cast<const short8*>(
                    (const char*)(&Ws[cur][0]) + bBase[nt] + (koff ^ bXor[nt]));
                acc[nt] = __builtin_amdgcn_mfma_f32_32x32x16_bf16(a, b, acc[nt], 0, 0, 0);
            }
        }

        if (pre) {
            // convert + write next Xs (after MFMAs so x-load latency is covered)
            #pragma unroll
            for (int p = 0; p < 2; ++p) {
                const int rr = xs_rr[p], s16 = xs_s16[p];
                union { unsigned short us[8]; short8 v; } pk;
                pk.us[0] = f2bf(xa[p].x); pk.us[1] = f2bf(xa[p].y);
                pk.us[2] = f2bf(xa[p].z); pk.us[3] = f2bf(xa[p].w);
                pk.us[4] = f2bf(xb[p].x); pk.us[5] = f2bf(xb[p].y);
                pk.us[6] = f2bf(xb[p].z); pk.us[7] = f2bf(xb[p].w);
                const int cb = (s16 * 16) ^ ((rr & 7) << 4);
                *reinterpret_cast<short8*>((char*)(&Xs[cur ^ 1][0]) + rr * 128 + cb) = pk.v;
            }
        }
        __syncthreads();   // drains vmcnt/lgkm: next buffer ready, cur reusable
    }

    // ---- epilogue (unchanged) ----
    #pragma unroll
    for (int nt = 0; nt < 3; ++nt) {
        const int gc  = cbase + nt * 32 + r;
        const int seg = gc >> 6;
        const int hh  = gc & 63;
        #pragma unroll
        for (int reg = 0; reg < 16; ++reg) {
            const int drow = (reg & 3) + 8 * (reg >> 2) + 4 * hi;
            const int grow = row0 + (wid >> 1) * 32 + drow;
            const float val = acc[nt][reg];
            if (seg == 0) {
                qbf[(size_t)grow * H + hh] = f2bf(val * 0.125f);
            } else if (seg == 1) {
                kbf[(size_t)grow * H + hh] = f2bf(val);
            } else {
                const int bb = grow >> 9, tt = grow & 511;
                vT[((size_t)bb * H + hh) * T + tt] = f2bf(val);
            }
        }
    }
}

// ---------------------------------------------------------------------------
// Kernel 2a: attention partials, ONE WAVE per (batch, chunk, 32-row q strip).
// No LDS, no barriers: K/V fragments read directly from global (L2/L3-hot),
// mask via precomputed bitmask words.  Swapped QK^T keeps softmax lane-local.
// Unit enumeration per batch: chunk c=0: strips 0..15; c=1: 4..15; c=2: 8..15;
// c=3: 12..15  -> 40 units.  Grid = 64*40 = 2560 one-wave blocks.
// ---------------------------------------------------------------------------
__global__ __launch_bounds__(64) void attn_unit(
    const unsigned short* __restrict__ qbf,
    const unsigned short* __restrict__ kbf,
    const unsigned short* __restrict__ vT,
    const unsigned int* __restrict__ mbits,
    unsigned short* __restrict__ O_part,
    float* __restrict__ m_part, float* __restrict__ l_part)
{
    const int lane = threadIdx.x;
    const int hi = lane >> 5, r = lane & 31;
    const int h4 = 4 * hi;

    const int u = blockIdx.x;
    const int b = u / NUNIT;
    const int t = u - b * NUNIT;
    int c, qs;
    if (t < 16)      { c = 0; qs = t; }
    else if (t < 28) { c = 1; qs = t - 12; }
    else if (t < 36) { c = 2; qs = t - 20; }
    else             { c = 3; qs = t - 24; }
    const int t0    = qs * 32;
    const int kbase = c * 128;
    const int tq    = t0 + r;
    const int nkb   = min(4, ((t0 + 31 - kbase) >> 5) + 1);
    const bool diag = (kbase + 128 > t0);    // else whole chunk is causal-valid

    // Q fragments (pre-scaled by 1/8)
    short8 qf[4];
    #pragma unroll
    for (int ks = 0; ks < 4; ++ks)
        qf[ks] = *reinterpret_cast<const short8*>(
            &qbf[((size_t)b * T + t0 + r) * H + ks * 16 + hi * 8]);

    // mask bit-words, one u32 per 32-key block (uniform address -> broadcast)
    unsigned int mw[4];
    #pragma unroll
    for (int kb = 0; kb < 4; ++kb)
        mw[kb] = mbits[b * 16 + (kbase >> 5) + kb];

    // ---- QK^T swapped, K straight from global ----
    f32x16 sc[4];
    #pragma unroll
    for (int kb = 0; kb < 4; ++kb) {
        if (kb < nkb) {
            f32x16 a = {};
            #pragma unroll
            for (int ks = 0; ks < 4; ++ks) {
                const short8 kf = *reinterpret_cast<const short8*>(
                    &kbf[((size_t)b * T + kbase + kb * 32 + r) * H + ks * 16 + hi * 8]);
                a = __builtin_amdgcn_mfma_f32_32x32x16_bf16(kf, qf[ks], a, 0, 0, 0);
            }
            sc[kb] = a;
        }
    }

    // ---- mask + local softmax ----
    float cmax = -INFINITY;
    if (diag) {
        #pragma unroll
        for (int kb = 0; kb < 4; ++kb) if (kb < nkb) {
            #pragma unroll
            for (int reg = 0; reg < 16; ++reg) {
                const int cr = (reg & 3) + 8 * (reg >> 2) + h4;
                float s = sc[kb][reg];
                const bool bad = !((mw[kb] >> cr) & 1u) || (kbase + kb * 32 + cr > tq);
                s = bad ? NEG_INF : s;
                sc[kb][reg] = s;
                cmax = fmaxf(cmax, s);
            }
        }
    } else {
        #pragma unroll
        for (int kb = 0; kb < 4; ++kb) {
            #pragma unroll
            for (int reg = 0; reg < 16; ++reg) {
                const int cr = (reg & 3) + 8 * (reg >> 2) + h4;
                float s = sc[kb][reg];
                s = ((mw[kb] >> cr) & 1u) ? s : NEG_INF;
                sc[kb][reg] = s;
                cmax = fmaxf(cmax, s);
            }
        }
    }
    cmax = fmaxf(cmax, __shfl_xor(cmax, 32));
    float csum = 0.f;
    #pragma unroll
    for (int kb = 0; kb < 4; ++kb) if (kb < nkb) {
        #pragma unroll
        for (int reg = 0; reg < 16; ++reg) {
            const float p = __expf(sc[kb][reg] - cmax);
            sc[kb][reg] = p;
            csum += p;
        }
    }
    csum += __shfl_xor(csum, 32);

    // ---- PV: P packed in-register (truncating), V straight from global ----
    f32x16 accO[2] = {};
    #pragma unroll
    for (int kb = 0; kb < 4; ++kb) if (kb < nkb) {
        unsigned int pk[8];
        #pragma unroll
        for (int j = 0; j < 8; ++j)
            pk[j] = bfpack_tr(sc[kb][2 * j], sc[kb][2 * j + 1]);
        #pragma unroll
        for (int hs = 0; hs < 2; ++hs) {
            const unsigned int p01 = pk[hs * 4 + 0], p23 = pk[hs * 4 + 1];
            const unsigned int p45 = pk[hs * 4 + 2], p67 = pk[hs * 4 + 3];
            const unsigned int sendA = hi ? p01 : p45;
            const unsigned int sendB = hi ? p23 : p67;
            const unsigned int recvA = (unsigned int)__shfl_xor((int)sendA, 32);
            const unsigned int recvB = (unsigned int)__shfl_xor((int)sendB, 32);
            union { unsigned int uu[4]; short8 s8; } aw;
            aw.uu[0] = hi ? recvA : p01;
            aw.uu[1] = hi ? recvB : p23;
            aw.uu[2] = hi ? p45 : recvA;
            aw.uu[3] = hi ? p67 : recvB;
            const int kcol = kbase + kb * 32 + hs * 16 + hi * 8;
            #pragma unroll
            for (int tile = 0; tile < 2; ++tile) {
                const short8 vb = *reinterpret_cast<const short8*>(
                    &vT[((size_t)b * H + r + 32 * tile) * T + kcol]);
                accO[tile] = __builtin_amdgcn_mfma_f32_32x32x16_bf16(
                    aw.s8, vb, accO[tile], 0, 0, 0);
            }
        }
    }

    // ---- write partials ----
    #pragma unroll
    for (int reg = 0; reg < 16; ++reg) {
        const int qrow = (reg & 3) + 8 * (reg >> 2) + h4;
        unsigned short* op = &O_part[((size_t)u * 32 + qrow) * H];
        op[r]      = f2bf(accO[0][reg]);
        op[r + 32] = f2bf(accO[1][reg]);
    }
    if (hi == 0) {
        m_part[u * 32 + r] = cmax;
        l_part[u * 32 + r] = csum;
    }
}

// ---------------------------------------------------------------------------
// Kernel 2b: combine partials and normalize.  One block per (batch, 128-row
// group); rows in group g merge nc = g+1 chunk partials.
// ---------------------------------------------------------------------------
__global__ __launch_bounds__(256) void attn_comb(
    const unsigned short* __restrict__ O_part,
    const float* __restrict__ m_part, const float* __restrict__ l_part,
    float* __restrict__ out)
{
    const int b    = blockIdx.x >> 2;
    const int g    = blockIdx.x & 3;      // 128-row group == chunk count - 1
    const int nc   = g + 1;
    const int tid  = threadIdx.x;
    const int col8 = (tid & 7) * 8;
    const int cb[4] = { 0, 16, 28, 36 };  // unit base per chunk

    #pragma unroll
    for (int pass = 0; pass < 4; ++pass) {
        const int row = g * 128 + pass * 32 + (tid >> 3);
        const int qs  = row >> 5;

        float mstar = -INFINITY;
        float mi[4], li[4];
        int off[4];
        #pragma unroll
        for (int c = 0; c < 4; ++c) {
            if (c < nc) {
                const int idx = cb[c] + qs - 4 * c;
                off[c] = (b * NUNIT + idx) * 32 + (row & 31);
                mi[c] = m_part[off[c]];
                li[c] = l_part[off[c]];
                mstar = fmaxf(mstar, mi[c]);
            }
        }
        float lsum = 0.f, fc[4];
        #pragma unroll
        for (int c = 0; c < 4; ++c) {
            if (c < nc) {
                fc[c] = __expf(mi[c] - mstar);
                lsum += fc[c] * li[c];
            }
        }
        const float inv = 1.f / lsum;

        float acc[8] = {};
        #pragma unroll
        for (int c = 0; c < 4; ++c) {
            if (c < nc) {
                union { short8 v; unsigned short us[8]; } o;
                o.v = *reinterpret_cast<const short8*>(
                    &O_part[(size_t)off[c] * H + col8]);
                #pragma unroll
                for (int j = 0; j < 8; ++j)
                    acc[j] += fc[c] * bf2f(o.us[j]);
            }
        }

        float* op = &out[((size_t)b * T + row) * H + col8];
        float4 lo4 = { acc[0] * inv, acc[1] * inv, acc[2] * inv, acc[3] * inv };
        float4 hi4 = { acc[4] * inv, acc[5] * inv, acc[6] * inv, acc[7] * inv };
        *reinterpret_cast<float4*>(op)     = lo4;
        *reinterpret_cast<float4*>(op + 4) = hi4;
    }
}

// ---------------------------------------------------------------------------
extern "C" void kernel_launch(void* const* d_in, const int* in_sizes, int n_in,
                              void* d_out, int out_size, void* d_ws, size_t ws_size,
                              hipStream_t stream) {
    const float* x         = (const float*)d_in[0];
    const int*   attn_mask = (const int*)d_in[1];
    const float* Wk        = (const float*)d_in[2];
    const float* Wq        = (const float*)d_in[3];
    const float* Wv        = (const float*)d_in[4];
    float* out = (float*)d_out;

    unsigned short* qbf    = (unsigned short*)d_ws;                      // 4 MB
    unsigned short* kbf    = qbf + (size_t)B * T * H;                    // 4 MB
    unsigned short* vT     = kbf + (size_t)B * T * H;                    // 4 MB
    unsigned short* WT_swz = vT  + (size_t)B * T * H;                    // 192 KB
    unsigned short* O_part = WT_swz + (size_t)PN * E;                    // 10.5 MB
    float*          m_part = (float*)(O_part + (size_t)B * NUNIT * 32 * H);
    float*          l_part = m_part + (size_t)B * NUNIT * 32;            // 328 KB ea
    unsigned int*   mbits  = (unsigned int*)(l_part + (size_t)B * NUNIT * 32);

    prep<<<512, 256, 0, stream>>>(Wq, Wk, Wv, attn_mask, WT_swz, mbits);
    proj_gemm<<<(B * T) / PBM, 256, 0, stream>>>(x, WT_swz, qbf, kbf, vT);
    attn_unit<<<B * NUNIT, 64, 0, stream>>>(qbf, kbf, vT, mbits,
                                            O_part, m_part, l_part);
    attn_comb<<<B * 4, 256, 0, stream>>>(O_part, m_part, l_part, out);
}